// Round 1
// baseline (705.247 us; speedup 1.0000x reference)
//
#include <hip/hip_runtime.h>

#define MDIM 8192
#define NDIM 4096
#define KDIM 4096
#define BK 32

typedef unsigned short u16;
typedef __attribute__((ext_vector_type(8))) short short8;
typedef __attribute__((ext_vector_type(4))) float f32x4;

// ---------- helpers ----------
__device__ __forceinline__ u16 f2b(float f) {  // fp32 -> bf16 RNE
  unsigned u = __float_as_uint(f);
  u += 0x7FFFu + ((u >> 16) & 1u);
  return (u16)(u >> 16);
}
__device__ __forceinline__ unsigned pk2(float a, float b) {
  return (unsigned)f2b(a) | ((unsigned)f2b(b) << 16);
}

// async global->LDS, 16B per lane, LDS dst = wave-uniform base + lane*16
__device__ __forceinline__ void async16(const u16* g, u16* l) {
  __builtin_amdgcn_global_load_lds(
      (const __attribute__((address_space(1))) unsigned*)g,
      (__attribute__((address_space(3))) unsigned*)l, 16, 0, 0);
}

// ---------- prep: x fp32 -> bf16 (8 elems/thread) ----------
__global__ __launch_bounds__(256) void k_prep_x(const float4* __restrict__ x,
                                                uint4* __restrict__ xb) {
  const int i = blockIdx.x * 256 + threadIdx.x;
  float4 a = x[2 * i], b = x[2 * i + 1];
  uint4 o;
  o.x = pk2(a.x, a.y); o.y = pk2(a.z, a.w);
  o.z = pk2(b.x, b.y); o.w = pk2(b.z, b.w);
  xb[i] = o;
}

// ---------- prep: W = mu + exp(sig)*eps -> bf16, + KL partials ----------
__global__ __launch_bounds__(256) void k_prep_w(const float4* __restrict__ mu,
                                                const float4* __restrict__ sg,
                                                const float4* __restrict__ ep,
                                                uint4* __restrict__ wb,
                                                float* __restrict__ partials) {
  const int i = blockIdx.x * 256 + threadIdx.x;
  float part = 0.f;
  uint4 o;
  {
    float4 m = mu[2 * i], s = sg[2 * i], e = ep[2 * i];
    float e0 = __expf(s.x), e1 = __expf(s.y), e2 = __expf(s.z), e3 = __expf(s.w);
    o.x = pk2(m.x + e0 * e.x, m.y + e1 * e.y);
    o.y = pk2(m.z + e2 * e.z, m.w + e3 * e.w);
    part += (1.f + 2.f * s.x - m.x * m.x - e0 * e0)
          + (1.f + 2.f * s.y - m.y * m.y - e1 * e1)
          + (1.f + 2.f * s.z - m.z * m.z - e2 * e2)
          + (1.f + 2.f * s.w - m.w * m.w - e3 * e3);
  }
  {
    float4 m = mu[2 * i + 1], s = sg[2 * i + 1], e = ep[2 * i + 1];
    float e0 = __expf(s.x), e1 = __expf(s.y), e2 = __expf(s.z), e3 = __expf(s.w);
    o.z = pk2(m.x + e0 * e.x, m.y + e1 * e.y);
    o.w = pk2(m.z + e2 * e.z, m.w + e3 * e.w);
    part += (1.f + 2.f * s.x - m.x * m.x - e0 * e0)
          + (1.f + 2.f * s.y - m.y * m.y - e1 * e1)
          + (1.f + 2.f * s.z - m.z * m.z - e2 * e2)
          + (1.f + 2.f * s.w - m.w * m.w - e3 * e3);
  }
  wb[i] = o;
  // block reduction -> one partial per block (deterministic, no atomics)
  for (int off = 32; off; off >>= 1) part += __shfl_down(part, off, 64);
  __shared__ float red[4];
  const int lane = threadIdx.x & 63, wv = threadIdx.x >> 6;
  if (lane == 0) red[wv] = part;
  __syncthreads();
  if (threadIdx.x == 0)
    partials[blockIdx.x] = red[0] + red[1] + red[2] + red[3];
}

// ---------- bias sample + final KL ----------
__global__ __launch_bounds__(256) void k_bias(const float* __restrict__ bmu,
                                              const float* __restrict__ bsg,
                                              const float* __restrict__ bep,
                                              float* __restrict__ bias,
                                              const float* __restrict__ partials,
                                              int nPart,
                                              float* __restrict__ klOut) {
  float part = 0.f;
  for (int i = threadIdx.x; i < NDIM; i += 256) {
    float s = bsg[i], m = bmu[i];
    float es = __expf(s);
    bias[i] = m + es * bep[i];
    part += 1.f + 2.f * s - m * m - es * es;
  }
  for (int i = threadIdx.x; i < nPart; i += 256) part += partials[i];
  for (int off = 32; off; off >>= 1) part += __shfl_down(part, off, 64);
  __shared__ float red[4];
  const int lane = threadIdx.x & 63, wv = threadIdx.x >> 6;
  if (lane == 0) red[wv] = part;
  __syncthreads();
  if (threadIdx.x == 0) *klOut = -0.5f * (red[0] + red[1] + red[2] + red[3]);
}

// ---------- GEMM: C[m][n] = sum_k A[m][k]*B[n][k] + bias[n] ----------
// m97 structure: 128x128 tile, BK=32, 4 waves x 4x4 mfma_f32_16x16x32_bf16,
// global_load_lds width=16 staging, 2-barrier K-loop.
__global__ __launch_bounds__(256) void k_gemm(const u16* __restrict__ A,
                                              const u16* __restrict__ B,
                                              const float* __restrict__ bias,
                                              float* __restrict__ C) {
  __shared__ u16 sA[128 * BK];
  __shared__ u16 sB[128 * BK];
  const int t = threadIdx.x;
  const int wave = t >> 6, lane = t & 63;
  const int bm = blockIdx.x * 128;
  const int bn = blockIdx.y * 128;
  const int wm = (wave >> 1) * 64;   // wave's 64x64 quadrant
  const int wn = (wave & 1) * 64;

  // staging: wave w covers tile rows [w*32, w*32+32); 2 loads of 16 rows each.
  // lane L -> row base+L/4, elem offset (L&3)*8 (16B); LDS dst base+L*16 auto.
  const int srow = lane >> 2;
  const int scol = (lane & 3) * 8;
  const u16* gA0 = A + (size_t)(bm + wave * 32 + srow) * KDIM + scol;
  const u16* gA1 = gA0 + (size_t)16 * KDIM;
  const u16* gB0 = B + (size_t)(bn + wave * 32 + srow) * KDIM + scol;
  const u16* gB1 = gB0 + (size_t)16 * KDIM;
  u16* lA0 = &sA[(wave * 32) * BK];
  u16* lA1 = &sA[(wave * 32 + 16) * BK];
  u16* lB0 = &sB[(wave * 32) * BK];
  u16* lB1 = &sB[(wave * 32 + 16) * BK];

  const int fr = lane & 15;   // row (A) / col (B) within 16x16 tile
  const int fg = lane >> 4;   // k-group: holds k = fg*8 .. fg*8+7

  f32x4 acc[4][4] = {};

  for (int k0 = 0; k0 < KDIM; k0 += BK) {
    async16(gA0 + k0, lA0);
    async16(gA1 + k0, lA1);
    async16(gB0 + k0, lB0);
    async16(gB1 + k0, lB1);
    __syncthreads();  // drains vmcnt then barrier

    short8 af[4], bf[4];
#pragma unroll
    for (int i = 0; i < 4; ++i) {
      af[i] = *(const short8*)&sA[(wm + i * 16 + fr) * BK + fg * 8];
      bf[i] = *(const short8*)&sB[(wn + i * 16 + fr) * BK + fg * 8];
    }
#pragma unroll
    for (int i = 0; i < 4; ++i)
#pragma unroll
      for (int j = 0; j < 4; ++j)
        acc[i][j] = __builtin_amdgcn_mfma_f32_16x16x32_bf16(af[i], bf[j],
                                                            acc[i][j], 0, 0, 0);
    __syncthreads();  // all waves done reading before next staging overwrite
  }

  // epilogue: C/D layout col=lane&15, row=(lane>>4)*4+reg  [m89-verified]
#pragma unroll
  for (int j = 0; j < 4; ++j) {
    const int gn = bn + wn + j * 16 + fr;
    const float bv = bias[gn];
#pragma unroll
    for (int i = 0; i < 4; ++i) {
      const int gm0 = bm + wm + i * 16 + fg * 4;
      float* Cp = C + (size_t)gm0 * NDIM + gn;
#pragma unroll
      for (int r = 0; r < 4; ++r)
        Cp[(size_t)r * NDIM] = acc[i][j][r] + bv;
    }
  }
}

// ---------- launch ----------
extern "C" void kernel_launch(void* const* d_in, const int* in_sizes, int n_in,
                              void* d_out, int out_size, void* d_ws, size_t ws_size,
                              hipStream_t stream) {
  const float* x    = (const float*)d_in[0];
  const float* wmu  = (const float*)d_in[1];
  const float* wsig = (const float*)d_in[2];
  const float* bmu  = (const float*)d_in[3];
  const float* bsig = (const float*)d_in[4];
  const float* ew   = (const float*)d_in[5];
  const float* eb   = (const float*)d_in[6];
  float* out = (float*)d_out;

  char* ws = (char*)d_ws;
  u16*   xb       = (u16*)ws;                          // 67108864 B
  u16*   wb       = (u16*)(ws + 67108864);             // 33554432 B
  float* bias     = (float*)(ws + 100663296);          // 16384 B
  float* partials = (float*)(ws + 100679680);          // 8192*4 B

  // W sample + KL partials (8192 blocks x 256 thr x 8 elems)
  k_prep_w<<<8192, 256, 0, stream>>>((const float4*)wmu, (const float4*)wsig,
                                     (const float4*)ew, (uint4*)wb, partials);
  // x -> bf16
  k_prep_x<<<16384, 256, 0, stream>>>((const float4*)x, (uint4*)xb);
  // bias sample + KL finalize (single block; stream order guarantees partials ready)
  k_bias<<<1, 256, 0, stream>>>(bmu, bsig, eb, bias, partials, 8192,
                                out + (size_t)MDIM * NDIM);
  // GEMM
  dim3 grid(MDIM / 128, NDIM / 128);
  k_gemm<<<grid, 256, 0, stream>>>(xb, wb, bias, out);
}

// Round 2
// 671.804 us; speedup vs baseline: 1.0498x; 1.0498x over previous
//
#include <hip/hip_runtime.h>

#define MDIM 8192
#define NDIM 4096
#define KDIM 4096
#define BK 32

typedef unsigned short u16;
typedef __attribute__((ext_vector_type(8))) short short8;
typedef __attribute__((ext_vector_type(4))) float f32x4;

// ---------- helpers ----------
__device__ __forceinline__ u16 f2b(float f) {  // fp32 -> bf16 RNE
  unsigned u = __float_as_uint(f);
  u += 0x7FFFu + ((u >> 16) & 1u);
  return (u16)(u >> 16);
}
__device__ __forceinline__ unsigned pk2(float a, float b) {
  return (unsigned)f2b(a) | ((unsigned)f2b(b) << 16);
}

// async global->LDS, 16B per lane, LDS dst = wave-uniform base + lane*16
__device__ __forceinline__ void async16(const u16* g, u16* l) {
  __builtin_amdgcn_global_load_lds(
      (const __attribute__((address_space(1))) unsigned*)g,
      (__attribute__((address_space(3))) unsigned*)l, 16, 0, 0);
}

// ---------- fused prep: W sample + KL partials (blocks < 8192),
//            x fp32->bf16 (blocks >= 8192, 16 elems/thread) ----------
__global__ __launch_bounds__(256) void k_prep(const float4* __restrict__ wmu,
                                              const float4* __restrict__ wsg,
                                              const float4* __restrict__ wep,
                                              uint4* __restrict__ wb,
                                              const float4* __restrict__ x,
                                              uint4* __restrict__ xb,
                                              float* __restrict__ partials) {
  const int bx = blockIdx.x;
  if (bx < 8192) {
    // ---- W = mu + exp(sig)*eps -> bf16, KL partial ----
    const int i = bx * 256 + (int)threadIdx.x;
    float part = 0.f;
    uint4 o;
    {
      float4 m = wmu[2 * i], s = wsg[2 * i], e = wep[2 * i];
      float e0 = __expf(s.x), e1 = __expf(s.y), e2 = __expf(s.z), e3 = __expf(s.w);
      o.x = pk2(m.x + e0 * e.x, m.y + e1 * e.y);
      o.y = pk2(m.z + e2 * e.z, m.w + e3 * e.w);
      part += (1.f + 2.f * s.x - m.x * m.x - e0 * e0)
            + (1.f + 2.f * s.y - m.y * m.y - e1 * e1)
            + (1.f + 2.f * s.z - m.z * m.z - e2 * e2)
            + (1.f + 2.f * s.w - m.w * m.w - e3 * e3);
    }
    {
      float4 m = wmu[2 * i + 1], s = wsg[2 * i + 1], e = wep[2 * i + 1];
      float e0 = __expf(s.x), e1 = __expf(s.y), e2 = __expf(s.z), e3 = __expf(s.w);
      o.z = pk2(m.x + e0 * e.x, m.y + e1 * e.y);
      o.w = pk2(m.z + e2 * e.z, m.w + e3 * e.w);
      part += (1.f + 2.f * s.x - m.x * m.x - e0 * e0)
            + (1.f + 2.f * s.y - m.y * m.y - e1 * e1)
            + (1.f + 2.f * s.z - m.z * m.z - e2 * e2)
            + (1.f + 2.f * s.w - m.w * m.w - e3 * e3);
    }
    wb[i] = o;
    for (int off = 32; off; off >>= 1) part += __shfl_down(part, off, 64);
    __shared__ float red[4];
    const int lane = threadIdx.x & 63, wv = threadIdx.x >> 6;
    if (lane == 0) red[wv] = part;
    __syncthreads();
    if (threadIdx.x == 0)
      partials[bx] = red[0] + red[1] + red[2] + red[3];
  } else {
    // ---- x -> bf16, two strided chunks of 8 elems each ----
    const int i0 = (bx - 8192) * 256 + (int)threadIdx.x;
#pragma unroll
    for (int c = 0; c < 2; ++c) {
      const int i = i0 + c * (8192 * 256);
      float4 a = x[2 * i], b = x[2 * i + 1];
      uint4 o;
      o.x = pk2(a.x, a.y); o.y = pk2(a.z, a.w);
      o.z = pk2(b.x, b.y); o.w = pk2(b.z, b.w);
      xb[i] = o;
    }
  }
}

// ---------- bias sample + final KL (1024 threads, 1 block) ----------
__global__ __launch_bounds__(1024) void k_bias(const float* __restrict__ bmu,
                                               const float* __restrict__ bsg,
                                               const float* __restrict__ bep,
                                               float* __restrict__ bias,
                                               const float* __restrict__ partials,
                                               int nPart,
                                               float* __restrict__ klOut) {
  float part = 0.f;
  for (int i = threadIdx.x; i < NDIM; i += 1024) {
    float s = bsg[i], m = bmu[i];
    float es = __expf(s);
    bias[i] = m + es * bep[i];
    part += 1.f + 2.f * s - m * m - es * es;
  }
  for (int i = threadIdx.x; i < nPart; i += 1024) part += partials[i];
  for (int off = 32; off; off >>= 1) part += __shfl_down(part, off, 64);
  __shared__ float red[16];
  const int lane = threadIdx.x & 63, wv = threadIdx.x >> 6;
  if (lane == 0) red[wv] = part;
  __syncthreads();
  if (threadIdx.x == 0) {
    float s = 0.f;
#pragma unroll
    for (int w = 0; w < 16; ++w) s += red[w];
    *klOut = -0.5f * s;
  }
}

// ---------- GEMM: C[m][n] = sum_k A[m][k]*B[n][k] + bias[n] ----------
// m97 structure: 128x128 tile, BK=32, 4 waves x 4x4 mfma_f32_16x16x32_bf16,
// global_load_lds width=16 staging. L2-friendly 16x16 super-tile swizzle.
__global__ __launch_bounds__(256) void k_gemm(const u16* __restrict__ A,
                                              const u16* __restrict__ B,
                                              const float* __restrict__ bias,
                                              float* __restrict__ C) {
  __shared__ u16 sA[128 * BK];
  __shared__ u16 sB[128 * BK];
  const int t = threadIdx.x;
  const int wave = t >> 6, lane = t & 63;

  // swizzle: 2048 blocks -> 8 super-tiles of 256 blocks (16m x 16n each).
  // Resident cohort footprint: A 16MB + B 16MB -> fits aggregate L2.
  const int lin = blockIdx.x;
  const int tile = lin >> 8, within = lin & 255;
  const int tm = within & 15, tn = within >> 4;
  const int sm = tile & 3, sn = tile >> 2;
  const int bm = (sm * 16 + tm) * 128;
  const int bn = (sn * 16 + tn) * 128;

  const int wm = (wave >> 1) * 64;   // wave's 64x64 quadrant
  const int wn = (wave & 1) * 64;

  // staging: wave w covers tile rows [w*32, w*32+32); 2 loads of 16 rows each.
  const int srow = lane >> 2;
  const int scol = (lane & 3) * 8;
  const u16* gA0 = A + (size_t)(bm + wave * 32 + srow) * KDIM + scol;
  const u16* gA1 = gA0 + (size_t)16 * KDIM;
  const u16* gB0 = B + (size_t)(bn + wave * 32 + srow) * KDIM + scol;
  const u16* gB1 = gB0 + (size_t)16 * KDIM;
  u16* lA0 = &sA[(wave * 32) * BK];
  u16* lA1 = &sA[(wave * 32 + 16) * BK];
  u16* lB0 = &sB[(wave * 32) * BK];
  u16* lB1 = &sB[(wave * 32 + 16) * BK];

  const int fr = lane & 15;   // row (A) / col (B) within 16x16 tile
  const int fg = lane >> 4;   // k-group: holds k = fg*8 .. fg*8+7

  f32x4 acc[4][4] = {};

  for (int k0 = 0; k0 < KDIM; k0 += BK) {
    async16(gA0 + k0, lA0);
    async16(gA1 + k0, lA1);
    async16(gB0 + k0, lB0);
    async16(gB1 + k0, lB1);
    __syncthreads();  // drains vmcnt then barrier

    short8 af[4], bf[4];
#pragma unroll
    for (int i = 0; i < 4; ++i) {
      af[i] = *(const short8*)&sA[(wm + i * 16 + fr) * BK + fg * 8];
      bf[i] = *(const short8*)&sB[(wn + i * 16 + fr) * BK + fg * 8];
    }
#pragma unroll
    for (int i = 0; i < 4; ++i)
#pragma unroll
      for (int j = 0; j < 4; ++j)
        acc[i][j] = __builtin_amdgcn_mfma_f32_16x16x32_bf16(af[i], bf[j],
                                                            acc[i][j], 0, 0, 0);
    __syncthreads();  // all waves done reading before next staging overwrite
  }

  // epilogue: C/D layout col=lane&15, row=(lane>>4)*4+reg  [m89-verified]
#pragma unroll
  for (int j = 0; j < 4; ++j) {
    const int gn = bn + wn + j * 16 + fr;
    const float bv = bias[gn];
#pragma unroll
    for (int i = 0; i < 4; ++i) {
      const int gm0 = bm + wm + i * 16 + fg * 4;
      float* Cp = C + (size_t)gm0 * NDIM + gn;
#pragma unroll
      for (int r = 0; r < 4; ++r)
        Cp[(size_t)r * NDIM] = acc[i][j][r] + bv;
    }
  }
}

// ---------- launch ----------
extern "C" void kernel_launch(void* const* d_in, const int* in_sizes, int n_in,
                              void* d_out, int out_size, void* d_ws, size_t ws_size,
                              hipStream_t stream) {
  const float* x    = (const float*)d_in[0];
  const float* wmu  = (const float*)d_in[1];
  const float* wsig = (const float*)d_in[2];
  const float* bmu  = (const float*)d_in[3];
  const float* bsig = (const float*)d_in[4];
  const float* ew   = (const float*)d_in[5];
  const float* eb   = (const float*)d_in[6];
  float* out = (float*)d_out;

  char* ws = (char*)d_ws;
  u16*   xb       = (u16*)ws;                          // 67108864 B
  u16*   wb       = (u16*)(ws + 67108864);             // 33554432 B
  float* bias     = (float*)(ws + 100663296);          // 16384 B
  float* partials = (float*)(ws + 100679680);          // 8192*4 B

  // fused W-sample/KL-partials + x-cast (one streaming dispatch)
  k_prep<<<16384, 256, 0, stream>>>((const float4*)wmu, (const float4*)wsig,
                                    (const float4*)ew, (uint4*)wb,
                                    (const float4*)x, (uint4*)xb, partials);
  // bias sample + KL finalize
  k_bias<<<1, 1024, 0, stream>>>(bmu, bsig, eb, bias, partials, 8192,
                                 out + (size_t)MDIM * NDIM);
  // GEMM (1-D grid, swizzled internally)
  k_gemm<<<2048, 256, 0, stream>>>(xb, wb, bias, out);
}